// Round 8
// baseline (404.102 us; speedup 1.0000x reference)
//
#include <hip/hip_runtime.h>
#include <hip/hip_bf16.h>

typedef __attribute__((ext_vector_type(4))) float  f32x4;
typedef __attribute__((ext_vector_type(8))) short  short8;
typedef __attribute__((ext_vector_type(4))) short  short4v;
typedef __attribute__((ext_vector_type(4))) unsigned int u32x4;

__device__ __forceinline__ unsigned short f32_to_bf16(float f) {
    union { float f; unsigned u; } v; v.f = f;
    unsigned r = v.u + 0x7FFFu + ((v.u >> 16) & 1u);   // RNE
    return (unsigned short)(r >> 16);
}
__device__ __forceinline__ unsigned pk_bf16(float a, float b) {
    return (unsigned)f32_to_bf16(a) | ((unsigned)f32_to_bf16(b) << 16);
}
__device__ __forceinline__ float bf16_to_f32(unsigned short h) {
    union { unsigned u; float f; } v; v.u = ((unsigned)h) << 16; return v.f;
}
__device__ __forceinline__ void gload_lds16(const void* g, void* l) {
    __builtin_amdgcn_global_load_lds(
        (const __attribute__((address_space(1))) unsigned int*)g,
        (__attribute__((address_space(3))) unsigned int*)l,
        16, 0, 0);
}

// ---------------- transpose + fp32->bf16 convert ----------------
__global__ __launch_bounds__(256) void transpose_to_bf16(
    const float* __restrict__ src, unsigned short* __restrict__ dst,
    int R, int Cin, int Cpad) {
    __shared__ float tile[32][33];
    const int tx = threadIdx.x, ty = threadIdx.y;
    const int c0 = blockIdx.x * 32, r0 = blockIdx.y * 32;
#pragma unroll
    for (int i = 0; i < 4; ++i) {
        int r = r0 + ty + i * 8, c = c0 + tx;
        float v = 0.f;
        if (r < R && c < Cin) v = src[(size_t)r * Cin + c];
        tile[ty + i * 8][tx] = v;
    }
    __syncthreads();
#pragma unroll
    for (int i = 0; i < 4; ++i) {
        int c = c0 + ty + i * 8, r = r0 + tx;
        if (c < Cpad && r < R)
            dst[(size_t)c * R + r] = f32_to_bf16(tile[tx][ty + i * 8]);
    }
}

// ---------------- bias[c] = -sum_d mean[d] * Mt[c][d] ----------------
__global__ __launch_bounds__(256) void bias_kernel(
    const float* __restrict__ mean, const unsigned short* __restrict__ Mt,
    float* __restrict__ bias, int D) {
    const int c = blockIdx.x;
    const unsigned short* row = Mt + (size_t)c * D;
    float s = 0.f;
    for (int d0 = threadIdx.x * 8; d0 < D; d0 += 256 * 8) {
        short4v h0 = *(const short4v*)&row[d0];
        short4v h1 = *(const short4v*)&row[d0 + 4];
        f32x4  m0 = *(const f32x4*)&mean[d0];
        f32x4  m1 = *(const f32x4*)&mean[d0 + 4];
#pragma unroll
        for (int j = 0; j < 4; ++j) {
            s += bf16_to_f32((unsigned short)h0[j]) * m0[j];
            s += bf16_to_f32((unsigned short)h1[j]) * m1[j];
        }
    }
#pragma unroll
    for (int off = 32; off > 0; off >>= 1) s += __shfl_down(s, off);
    __shared__ float red[4];
    const int lane = threadIdx.x & 63, w = threadIdx.x >> 6;
    if (lane == 0) red[w] = s;
    __syncthreads();
    if (threadIdx.x == 0) bias[c] = -(red[0] + red[1] + red[2] + red[3]);
}

// ================= deep-pipelined GEMM: 256x128 tile, BK=64, 512 thr, 3-buf LDS =================
#define P_BM 256
#define P_BN 128
#define P_BK 64
#define ABUF 16384   /* elements (256*64) */
#define BUFE 24576   /* per-buffer elements */
#define P_LDS_BYTES (3 * BUFE * 2)

template<int P0, int P1>
__device__ __forceinline__ void stage_part(
    const unsigned short* __restrict__ g, int K, int k0,
    unsigned short* l, int tid) {
#pragma unroll
    for (int p = P0; p < P1; ++p) {
        unsigned lin = ((unsigned)p * 512 + (unsigned)tid) * 16u;
        unsigned row = lin >> 7;
        unsigned colb = (lin ^ ((row & 7u) << 4)) & 127u;
        gload_lds16((const char*)g + (size_t)row * K * 2 + (size_t)k0 * 2 + colb,
                    (char*)l + lin);
    }
}

__device__ __forceinline__ short8 lfrag(const unsigned short* base, unsigned row, unsigned cb) {
    unsigned lin = row * 128u + cb;
    unsigned b = lin ^ ((row & 7u) << 4);
    return *(const short8*)((const char*)base + b);
}

// convert 32 fp32 (av[8] f32x4) -> 4 x ds_write_b128 (bf16, swizzled)
__device__ __forceinline__ void convert_write(const f32x4* av, unsigned short* abase_ptr,
                                              unsigned abase, unsigned axor) {
#pragma unroll
    for (int c = 0; c < 4; ++c) {
        u32x4 wv;
        wv[0] = pk_bf16(av[2 * c][0], av[2 * c][1]);
        wv[1] = pk_bf16(av[2 * c][2], av[2 * c][3]);
        wv[2] = pk_bf16(av[2 * c + 1][0], av[2 * c + 1][1]);
        wv[3] = pk_bf16(av[2 * c + 1][2], av[2 * c + 1][3]);
        unsigned byteoff = (abase + (unsigned)c * 16u) ^ axor;
        *(u32x4*)((char*)abase_ptr + byteoff) = wv;
    }
}

// ---------------- GEMM1 (bf16 both operands, gload_lds): chunked XCD decode ----------------
__global__ __launch_bounds__(512) void gemm1_p(
    const unsigned short* __restrict__ A, const unsigned short* __restrict__ Bt,
    unsigned short* __restrict__ C, int M, int N, int K) {
    extern __shared__ unsigned short lds[];
    const int bid = blockIdx.x;
    const int x = bid & 7, i = bid >> 3;
    const int col0 = (x * 8 + (i >> 2)) * P_BN;
    const int row0 = (i & 3) * P_BM;
    const int tid = threadIdx.x;
    const int w = tid >> 6, lane = tid & 63;
    const int wm = w >> 1, wn = w & 1;
    const int lr = lane & 15, hi = lane >> 4;
    const int arow = wm * 64 + lr;
    const int brow = wn * 64 + lr;

    const unsigned short* Ag = A + (size_t)row0 * K;
    const unsigned short* Bg = Bt + (size_t)col0 * K;

    f32x4 acc[4][4];
#pragma unroll
    for (int m = 0; m < 4; ++m)
#pragma unroll
        for (int n = 0; n < 4; ++n) acc[m][n] = (f32x4){0.f, 0.f, 0.f, 0.f};

    const int NT = K / P_BK;
    stage_part<0, 4>(Ag, K, 0, lds, tid);
    stage_part<0, 2>(Bg, K, 0, lds + ABUF, tid);
    stage_part<0, 4>(Ag, K, P_BK, lds + BUFE, tid);
    stage_part<0, 2>(Bg, K, P_BK, lds + BUFE + ABUF, tid);

    for (int t = 0; t < NT; ++t) {
        if (t + 1 < NT) asm volatile("s_waitcnt vmcnt(6)" ::: "memory");
        else            asm volatile("s_waitcnt vmcnt(0)" ::: "memory");
        __builtin_amdgcn_sched_barrier(0);
        __builtin_amdgcn_s_barrier();
        __builtin_amdgcn_sched_barrier(0);

        unsigned short* buf = lds + (t % 3) * BUFE;
        const unsigned short* As = buf;
        const unsigned short* Bs = buf + ABUF;
        unsigned short* nbuf = lds + ((t + 2) % 3) * BUFE;
        const bool st = (t + 2 < NT);
        const int k2 = (t + 2) * P_BK;

        if (st) stage_part<0, 2>(Ag, K, k2, nbuf, tid);

        short8 bf[4][2];
#pragma unroll
        for (int n = 0; n < 4; ++n)
#pragma unroll
            for (int s = 0; s < 2; ++s)
                bf[n][s] = lfrag(Bs, brow + n * 16, s * 64 + hi * 16);
        short8 af0[2][2];
#pragma unroll
        for (int m = 0; m < 2; ++m)
#pragma unroll
            for (int s = 0; s < 2; ++s)
                af0[m][s] = lfrag(As, arow + m * 16, s * 64 + hi * 16);

        if (st) stage_part<2, 4>(Ag, K, k2, nbuf, tid);

        __builtin_amdgcn_s_setprio(1);
#pragma unroll
        for (int m = 0; m < 2; ++m)
#pragma unroll
            for (int n = 0; n < 4; ++n)
#pragma unroll
                for (int s = 0; s < 2; ++s)
                    acc[m][n] = __builtin_amdgcn_mfma_f32_16x16x32_bf16(af0[m][s], bf[n][s], acc[m][n], 0, 0, 0);
        __builtin_amdgcn_s_setprio(0);

        short8 af1[2][2];
#pragma unroll
        for (int m = 0; m < 2; ++m)
#pragma unroll
            for (int s = 0; s < 2; ++s)
                af1[m][s] = lfrag(As, arow + 32 + m * 16, s * 64 + hi * 16);

        if (st) stage_part<0, 2>(Bg, K, k2, nbuf + ABUF, tid);

        __builtin_amdgcn_s_setprio(1);
#pragma unroll
        for (int m = 0; m < 2; ++m)
#pragma unroll
            for (int n = 0; n < 4; ++n)
#pragma unroll
                for (int s = 0; s < 2; ++s)
                    acc[2 + m][n] = __builtin_amdgcn_mfma_f32_16x16x32_bf16(af1[m][s], bf[n][s], acc[2 + m][n], 0, 0, 0);
        __builtin_amdgcn_s_setprio(0);
    }

#pragma unroll
    for (int m = 0; m < 4; ++m) {
        int rg = row0 + wm * 64 + m * 16 + hi * 4;
#pragma unroll
        for (int n = 0; n < 4; ++n) {
            int cg = col0 + wn * 64 + n * 16 + lr;
#pragma unroll
            for (int j = 0; j < 4; ++j)
                C[(size_t)(rg + j) * N + cg] = f32_to_bf16(acc[m][n][j]);
        }
    }
}

// ---------------- GEMM2 fused-convert: out = feats(f32) @ Mt(bf16)^T + bias ----------------
// A reg-staged: load fp32 tile t+2 at iter t, convert+ds_write tile t+1 after barrier at t.
// vmcnt ledger (B only; A-reg deps tracked by compiler): issues/iter = 8A + 2B -> vmcnt(10).
__global__ __launch_bounds__(512) void gemm2_f32p(
    const float* __restrict__ A, const unsigned short* __restrict__ Bt,
    const float* __restrict__ bias, float* __restrict__ out,
    int M, int N, int K, int Nout) {
    extern __shared__ unsigned short lds[];
    const int bid = blockIdx.x;
    const int x = bid & 7, i = bid >> 3;
    const int row0 = (x * 4 + (i >> 3)) * P_BM;
    const int col0 = (i & 7) * P_BN;
    const int tid = threadIdx.x;
    const int w = tid >> 6, lane = tid & 63;
    const int wm = w >> 1, wn = w & 1;
    const int lr = lane & 15, hi = lane >> 4;
    const int arow = wm * 64 + lr;
    const int brow = wn * 64 + lr;

    const unsigned short* Bg = Bt + (size_t)col0 * K;
    // A staging map: thread -> row ra = tid>>1, k-half kh = (tid&1)*32
    const int ra = tid >> 1;
    const int kh = (tid & 1) * 32;
    const float* Ar = A + (size_t)(row0 + ra) * K + kh;
    const unsigned abase = (unsigned)ra * 128u + (unsigned)kh * 2u;
    const unsigned axor = ((unsigned)ra & 7u) << 4;

    f32x4 acc[4][4];
#pragma unroll
    for (int m = 0; m < 4; ++m)
#pragma unroll
        for (int n = 0; n < 4; ++n) acc[m][n] = (f32x4){0.f, 0.f, 0.f, 0.f};

    f32x4 av[8];
    const int NT = K / P_BK;

    // prologue: B(0)->buf0, B(1)->buf1; A(0) via regs -> buf0; A(1) -> regs
    stage_part<0, 2>(Bg, K, 0, lds + ABUF, tid);
    stage_part<0, 2>(Bg, K, P_BK, lds + BUFE + ABUF, tid);
#pragma unroll
    for (int j = 0; j < 8; ++j) av[j] = *(const f32x4*)(Ar + j * 4);
    convert_write(av, lds, abase, axor);
#pragma unroll
    for (int j = 0; j < 8; ++j) av[j] = *(const f32x4*)(Ar + P_BK + j * 4);

    for (int t = 0; t < NT; ++t) {
        if (t + 1 < NT) asm volatile("s_waitcnt vmcnt(10)" ::: "memory");
        else            asm volatile("s_waitcnt vmcnt(0)" ::: "memory");
        asm volatile("s_waitcnt lgkmcnt(0)" ::: "memory");
        __builtin_amdgcn_sched_barrier(0);
        __builtin_amdgcn_s_barrier();
        __builtin_amdgcn_sched_barrier(0);

        unsigned short* buf = lds + (t % 3) * BUFE;
        const unsigned short* As = buf;
        const unsigned short* Bs = buf + ABUF;

        // frag reads first (LDS pipe), then staging work
        short8 bf[4][2];
#pragma unroll
        for (int n = 0; n < 4; ++n)
#pragma unroll
            for (int s = 0; s < 2; ++s)
                bf[n][s] = lfrag(Bs, brow + n * 16, s * 64 + hi * 16);
        short8 af0[2][2];
#pragma unroll
        for (int m = 0; m < 2; ++m)
#pragma unroll
            for (int s = 0; s < 2; ++s)
                af0[m][s] = lfrag(As, arow + m * 16, s * 64 + hi * 16);

        if (t + 1 < NT) {
            unsigned short* wbuf = lds + ((t + 1) % 3) * BUFE;
            convert_write(av, wbuf, abase, axor);   // consumes av (tile t+1)
        }
        if (t + 2 < NT) {
            const int k2 = (t + 2) * P_BK;
#pragma unroll
            for (int j = 0; j < 8; ++j) av[j] = *(const f32x4*)(Ar + k2 + j * 4);
        }

        __builtin_amdgcn_s_setprio(1);
#pragma unroll
        for (int m = 0; m < 2; ++m)
#pragma unroll
            for (int n = 0; n < 4; ++n)
#pragma unroll
                for (int s = 0; s < 2; ++s)
                    acc[m][n] = __builtin_amdgcn_mfma_f32_16x16x32_bf16(af0[m][s], bf[n][s], acc[m][n], 0, 0, 0);
        __builtin_amdgcn_s_setprio(0);

        short8 af1[2][2];
#pragma unroll
        for (int m = 0; m < 2; ++m)
#pragma unroll
            for (int s = 0; s < 2; ++s)
                af1[m][s] = lfrag(As, arow + 32 + m * 16, s * 64 + hi * 16);

        if (t + 2 < NT)
            stage_part<0, 2>(Bg, K, (t + 2) * P_BK, lds + ((t + 2) % 3) * BUFE + ABUF, tid);

        __builtin_amdgcn_s_setprio(1);
#pragma unroll
        for (int m = 0; m < 2; ++m)
#pragma unroll
            for (int n = 0; n < 4; ++n)
#pragma unroll
                for (int s = 0; s < 2; ++s)
                    acc[2 + m][n] = __builtin_amdgcn_mfma_f32_16x16x32_bf16(af1[m][s], bf[n][s], acc[2 + m][n], 0, 0, 0);
        __builtin_amdgcn_s_setprio(0);
    }

#pragma unroll
    for (int m = 0; m < 4; ++m) {
        int rg = row0 + wm * 64 + m * 16 + hi * 4;
#pragma unroll
        for (int n = 0; n < 4; ++n) {
            int cg = col0 + wn * 64 + n * 16 + lr;
            if (cg < Nout) {
                float bv = bias[cg];
#pragma unroll
                for (int j = 0; j < 4; ++j)
                    out[(size_t)(rg + j) * Nout + cg] = acc[m][n][j] + bv;
            }
        }
    }
}

extern "C" void kernel_launch(void* const* d_in, const int* in_sizes, int n_in,
                              void* d_out, int out_size, void* d_ws, size_t ws_size,
                              hipStream_t stream) {
    const float* feats = (const float*)d_in[0];   // [8192][8192]
    const float* mean  = (const float*)d_in[1];   // [8192]
    const float* comp  = (const float*)d_in[2];   // [2048][8192]
    const float* W     = (const float*)d_in[3];   // [2048][1000]
    float* out = (float*)d_out;                   // [8192][1000]

    const int N = 8192, D = 8192, Kp = 2048, C = 1000, Cp = 1024;

    char* ws = (char*)d_ws;
    unsigned short* Wt    = (unsigned short*)ws;                  // [Cp][Kp]   4 MB
    size_t off = (size_t)Cp * Kp * 2;
    unsigned short* compT = (unsigned short*)(ws + off);          // [D][Kp]   32 MB
    off += (size_t)D * Kp * 2;
    unsigned short* Mt    = (unsigned short*)(ws + off);          // [Cp][D]   16 MB
    off += (size_t)Cp * D * 2;
    float* bias           = (float*)(ws + off);                   // [Cp]

    dim3 tb(32, 8);
    transpose_to_bf16<<<dim3(Cp / 32, Kp / 32), tb, 0, stream>>>(W, Wt, Kp, C, Cp);
    transpose_to_bf16<<<dim3(D / 32, Kp / 32), tb, 0, stream>>>(comp, compT, Kp, D, D);

    hipFuncSetAttribute(reinterpret_cast<const void*>(gemm1_p),
                        hipFuncAttributeMaxDynamicSharedMemorySize, P_LDS_BYTES);
    hipFuncSetAttribute(reinterpret_cast<const void*>(gemm2_f32p),
                        hipFuncAttributeMaxDynamicSharedMemorySize, P_LDS_BYTES);

    // GEMM1: Mt[1024][8192] = Wt @ compT^T ; grid 4x64 = 256 = 1/CU
    gemm1_p<<<(Cp / P_BM) * (D / P_BN), 512, P_LDS_BYTES, stream>>>(
        Wt, compT, Mt, Cp, D, Kp);
    bias_kernel<<<Cp, 256, 0, stream>>>(mean, Mt, bias, D);

    // GEMM2 fused-convert: out[8192][1000] = feats @ Mt^T + bias ; grid 32x8 = 256 = 1/CU
    gemm2_f32p<<<(N / P_BM) * (Cp / P_BN), 512, P_LDS_BYTES, stream>>>(
        feats, Mt, bias, out, N, Cp, D, C);
}

// Round 9
// 294.185 us; speedup vs baseline: 1.3736x; 1.3736x over previous
//
#include <hip/hip_runtime.h>
#include <hip/hip_bf16.h>

typedef __attribute__((ext_vector_type(4))) float  f32x4;
typedef __attribute__((ext_vector_type(8))) short  short8;
typedef __attribute__((ext_vector_type(4))) short  short4v;

__device__ __forceinline__ unsigned short f32_to_bf16(float f) {
    union { float f; unsigned u; } v; v.f = f;
    unsigned r = v.u + 0x7FFFu + ((v.u >> 16) & 1u);   // RNE
    return (unsigned short)(r >> 16);
}
__device__ __forceinline__ float bf16_to_f32(unsigned short h) {
    union { unsigned u; float f; } v; v.u = ((unsigned)h) << 16; return v.f;
}
__device__ __forceinline__ void gload_lds16(const void* g, void* l) {
    __builtin_amdgcn_global_load_lds(
        (const __attribute__((address_space(1))) unsigned int*)g,
        (__attribute__((address_space(3))) unsigned int*)l,
        16, 0, 0);
}

// ---------------- transpose + fp32->bf16 convert ----------------
__global__ __launch_bounds__(256) void transpose_to_bf16(
    const float* __restrict__ src, unsigned short* __restrict__ dst,
    int R, int Cin, int Cpad) {
    __shared__ float tile[32][33];
    const int tx = threadIdx.x, ty = threadIdx.y;
    const int c0 = blockIdx.x * 32, r0 = blockIdx.y * 32;
#pragma unroll
    for (int i = 0; i < 4; ++i) {
        int r = r0 + ty + i * 8, c = c0 + tx;
        float v = 0.f;
        if (r < R && c < Cin) v = src[(size_t)r * Cin + c];
        tile[ty + i * 8][tx] = v;
    }
    __syncthreads();
#pragma unroll
    for (int i = 0; i < 4; ++i) {
        int c = c0 + ty + i * 8, r = r0 + tx;
        if (c < Cpad && r < R)
            dst[(size_t)c * R + r] = f32_to_bf16(tile[tx][ty + i * 8]);
    }
}

// ---------------- bias[c] = -sum_d mean[d] * Mt[c][d] ----------------
__global__ __launch_bounds__(256) void bias_kernel(
    const float* __restrict__ mean, const unsigned short* __restrict__ Mt,
    float* __restrict__ bias, int D) {
    const int c = blockIdx.x;
    const unsigned short* row = Mt + (size_t)c * D;
    float s = 0.f;
    for (int d0 = threadIdx.x * 8; d0 < D; d0 += 256 * 8) {
        short4v h0 = *(const short4v*)&row[d0];
        short4v h1 = *(const short4v*)&row[d0 + 4];
        f32x4  m0 = *(const f32x4*)&mean[d0];
        f32x4  m1 = *(const f32x4*)&mean[d0 + 4];
#pragma unroll
        for (int j = 0; j < 4; ++j) {
            s += bf16_to_f32((unsigned short)h0[j]) * m0[j];
            s += bf16_to_f32((unsigned short)h1[j]) * m1[j];
        }
    }
#pragma unroll
    for (int off = 32; off > 0; off >>= 1) s += __shfl_down(s, off);
    __shared__ float red[4];
    const int lane = threadIdx.x & 63, w = threadIdx.x >> 6;
    if (lane == 0) red[w] = s;
    __syncthreads();
    if (threadIdx.x == 0) bias[c] = -(red[0] + red[1] + red[2] + red[3]);
}

// ================= FAT kernel: GEMM1 (bids 0..511) || feats convert (bids 512..2559) =================
// GEMM1: Mt[1024][8192](bf16) = Wt[1024][2048] @ compT[8192][2048]^T, 128x128 tile, 256thr, 32KB LDS.
// gemm1 blocks FIRST in bid order -> all 512 co-resident at 2/CU from t=0 (no stragglers);
// convert blocks fill remaining block slots and stream HBM under gemm1's MFMA (m114 overlap).
#define FAT_G1 512
#define FAT_CV 2048

__global__ __launch_bounds__(256) void fat_g1c(
    const unsigned short* __restrict__ Wt, const unsigned short* __restrict__ compT,
    unsigned short* __restrict__ Mt,
    const float* __restrict__ feats, unsigned short* __restrict__ featsB) {
    __shared__ unsigned short As[128 * 64];
    __shared__ unsigned short Bs[128 * 64];
    const int bid = blockIdx.x;
    const int t = threadIdx.x;

    if (bid < FAT_G1) {
        // chunked XCD decode (x = physical XCD): col-panels [8x,8x+8) x all 8 rows
        const int x = bid & 7, i = bid >> 3;
        const int col0 = (x * 8 + (i >> 3)) * 128;
        const int row0 = (i & 7) * 128;
        const int Kk = 2048, Nn = 8192;

        const int lane = t & 63, w = t >> 6;
        const int wr = w >> 1, wc = w & 1;
        const int lr = lane & 15, hi = lane >> 4;

        f32x4 acc[4][4];
#pragma unroll
        for (int m = 0; m < 4; ++m)
#pragma unroll
            for (int n = 0; n < 4; ++n) acc[m][n] = (f32x4){0.f, 0.f, 0.f, 0.f};

        const int sr = t >> 3;
        const int sc = (t & 7) * 8;

        for (int k0 = 0; k0 < Kk; k0 += 64) {
#pragma unroll
            for (int i2 = 0; i2 < 4; ++i2) {
                int r = i2 * 32 + sr;
                gload_lds16(Wt + (size_t)(row0 + r) * Kk + (k0 + sc), &As[r * 64 + sc]);
                gload_lds16(compT + (size_t)(col0 + r) * Kk + (k0 + sc), &Bs[r * 64 + sc]);
            }
            __syncthreads();
#pragma unroll
            for (int s = 0; s < 2; ++s) {
                short8 a[4], bb[4];
#pragma unroll
                for (int m = 0; m < 4; ++m)
                    a[m] = *(const short8*)&As[(wr * 64 + m * 16 + lr) * 64 + s * 32 + hi * 8];
#pragma unroll
                for (int n = 0; n < 4; ++n)
                    bb[n] = *(const short8*)&Bs[(wc * 64 + n * 16 + lr) * 64 + s * 32 + hi * 8];
#pragma unroll
                for (int m = 0; m < 4; ++m)
#pragma unroll
                    for (int n = 0; n < 4; ++n)
                        acc[m][n] = __builtin_amdgcn_mfma_f32_16x16x32_bf16(a[m], bb[n], acc[m][n], 0, 0, 0);
            }
            __syncthreads();
        }
#pragma unroll
        for (int m = 0; m < 4; ++m) {
            int rg = row0 + wr * 64 + m * 16 + hi * 4;
#pragma unroll
            for (int n = 0; n < 4; ++n) {
                int cg = col0 + wc * 64 + n * 16 + lr;
#pragma unroll
                for (int j = 0; j < 4; ++j)
                    Mt[(size_t)(rg + j) * Nn + cg] = f32_to_bf16(acc[m][n][j]);
            }
        }
    } else {
        // ---- convert feats fp32 -> bf16 (64M elems), grid-stride ----
        const int cb = bid - FAT_G1;
        const size_t n = (size_t)8192 * 8192;
        size_t idx = ((size_t)cb * 256 + t) * 8;
        const size_t stride = (size_t)FAT_CV * 256 * 8;
        for (; idx < n; idx += stride) {
            f32x4 v0 = *(const f32x4*)(feats + idx);
            f32x4 v1 = *(const f32x4*)(feats + idx + 4);
            short8 h;
#pragma unroll
            for (int j = 0; j < 4; ++j) h[j] = (short)f32_to_bf16(v0[j]);
#pragma unroll
            for (int j = 0; j < 4; ++j) h[4 + j] = (short)f32_to_bf16(v1[j]);
            *(short8*)(featsB + idx) = h;
        }
    }
}

// ================= deep-pipelined GEMM2: 256x128 tile, BK=64, 512 thr, 3-buf LDS (R7-proven) =================
#define P_BM 256
#define P_BN 128
#define P_BK 64
#define ABUF 16384   /* elements (256*64) */
#define BUFE 24576   /* per-buffer elements */
#define P_LDS_BYTES (3 * BUFE * 2)

template<int P0, int P1>
__device__ __forceinline__ void stage_part(
    const unsigned short* __restrict__ g, int K, int k0,
    unsigned short* l, int tid) {
#pragma unroll
    for (int p = P0; p < P1; ++p) {
        unsigned lin = ((unsigned)p * 512 + (unsigned)tid) * 16u;
        unsigned row = lin >> 7;
        unsigned colb = (lin ^ ((row & 7u) << 4)) & 127u;
        gload_lds16((const char*)g + (size_t)row * K * 2 + (size_t)k0 * 2 + colb,
                    (char*)l + lin);
    }
}

__device__ __forceinline__ short8 lfrag(const unsigned short* base, unsigned row, unsigned cb) {
    unsigned lin = row * 128u + cb;
    unsigned b = lin ^ ((row & 7u) << 4);
    return *(const short8*)((const char*)base + b);
}

// chunked XCD decode: XCD x -> row panels [4x,4x+4) x all 8 cols (A panels L2-private)
__global__ __launch_bounds__(512) void gemm2_p(
    const unsigned short* __restrict__ A, const unsigned short* __restrict__ Bt,
    const float* __restrict__ bias, float* __restrict__ out,
    int M, int N, int K, int Nout) {
    extern __shared__ unsigned short lds[];
    const int bid = blockIdx.x;
    const int x = bid & 7, i = bid >> 3;
    const int row0 = (x * 4 + (i >> 3)) * P_BM;
    const int col0 = (i & 7) * P_BN;
    const int tid = threadIdx.x;
    const int w = tid >> 6, lane = tid & 63;
    const int wm = w >> 1, wn = w & 1;
    const int lr = lane & 15, hi = lane >> 4;
    const int arow = wm * 64 + lr;
    const int brow = wn * 64 + lr;

    const unsigned short* Ag = A + (size_t)row0 * K;
    const unsigned short* Bg = Bt + (size_t)col0 * K;

    f32x4 acc[4][4];
#pragma unroll
    for (int m = 0; m < 4; ++m)
#pragma unroll
        for (int n = 0; n < 4; ++n) acc[m][n] = (f32x4){0.f, 0.f, 0.f, 0.f};

    const int NT = K / P_BK;
    stage_part<0, 4>(Ag, K, 0, lds, tid);
    stage_part<0, 2>(Bg, K, 0, lds + ABUF, tid);
    stage_part<0, 4>(Ag, K, P_BK, lds + BUFE, tid);
    stage_part<0, 2>(Bg, K, P_BK, lds + BUFE + ABUF, tid);

    for (int t = 0; t < NT; ++t) {
        if (t + 1 < NT) asm volatile("s_waitcnt vmcnt(6)" ::: "memory");
        else            asm volatile("s_waitcnt vmcnt(0)" ::: "memory");
        __builtin_amdgcn_sched_barrier(0);
        __builtin_amdgcn_s_barrier();
        __builtin_amdgcn_sched_barrier(0);

        unsigned short* buf = lds + (t % 3) * BUFE;
        const unsigned short* As = buf;
        const unsigned short* Bs = buf + ABUF;
        unsigned short* nbuf = lds + ((t + 2) % 3) * BUFE;
        const bool st = (t + 2 < NT);
        const int k2 = (t + 2) * P_BK;

        if (st) stage_part<0, 2>(Ag, K, k2, nbuf, tid);

        short8 bf[4][2];
#pragma unroll
        for (int n = 0; n < 4; ++n)
#pragma unroll
            for (int s = 0; s < 2; ++s)
                bf[n][s] = lfrag(Bs, brow + n * 16, s * 64 + hi * 16);
        short8 af0[2][2];
#pragma unroll
        for (int m = 0; m < 2; ++m)
#pragma unroll
            for (int s = 0; s < 2; ++s)
                af0[m][s] = lfrag(As, arow + m * 16, s * 64 + hi * 16);

        if (st) stage_part<2, 4>(Ag, K, k2, nbuf, tid);

        __builtin_amdgcn_s_setprio(1);
#pragma unroll
        for (int m = 0; m < 2; ++m)
#pragma unroll
            for (int n = 0; n < 4; ++n)
#pragma unroll
                for (int s = 0; s < 2; ++s)
                    acc[m][n] = __builtin_amdgcn_mfma_f32_16x16x32_bf16(af0[m][s], bf[n][s], acc[m][n], 0, 0, 0);
        __builtin_amdgcn_s_setprio(0);

        short8 af1[2][2];
#pragma unroll
        for (int m = 0; m < 2; ++m)
#pragma unroll
            for (int s = 0; s < 2; ++s)
                af1[m][s] = lfrag(As, arow + 32 + m * 16, s * 64 + hi * 16);

        if (st) stage_part<0, 2>(Bg, K, k2, nbuf + ABUF, tid);

        __builtin_amdgcn_s_setprio(1);
#pragma unroll
        for (int m = 0; m < 2; ++m)
#pragma unroll
            for (int n = 0; n < 4; ++n)
#pragma unroll
                for (int s = 0; s < 2; ++s)
                    acc[2 + m][n] = __builtin_amdgcn_mfma_f32_16x16x32_bf16(af1[m][s], bf[n][s], acc[2 + m][n], 0, 0, 0);
        __builtin_amdgcn_s_setprio(0);
    }

#pragma unroll
    for (int m = 0; m < 4; ++m) {
        int rg = row0 + wm * 64 + m * 16 + hi * 4;
#pragma unroll
        for (int n = 0; n < 4; ++n) {
            int cg = col0 + wn * 64 + n * 16 + lr;
            if (cg < Nout) {
                float bv = bias[cg];
#pragma unroll
                for (int j = 0; j < 4; ++j)
                    out[(size_t)(rg + j) * Nout + cg] = acc[m][n][j] + bv;
            }
        }
    }
}

extern "C" void kernel_launch(void* const* d_in, const int* in_sizes, int n_in,
                              void* d_out, int out_size, void* d_ws, size_t ws_size,
                              hipStream_t stream) {
    const float* feats = (const float*)d_in[0];   // [8192][8192]
    const float* mean  = (const float*)d_in[1];   // [8192]
    const float* comp  = (const float*)d_in[2];   // [2048][8192]
    const float* W     = (const float*)d_in[3];   // [2048][1000]
    float* out = (float*)d_out;                   // [8192][1000]

    const int N = 8192, D = 8192, Kp = 2048, C = 1000, Cp = 1024;

    char* ws = (char*)d_ws;
    unsigned short* Wt    = (unsigned short*)ws;                  // [Cp][Kp]   4 MB
    size_t off = (size_t)Cp * Kp * 2;
    unsigned short* compT = (unsigned short*)(ws + off);          // [D][Kp]   32 MB
    off += (size_t)D * Kp * 2;
    unsigned short* Mt    = (unsigned short*)(ws + off);          // [Cp][D]   16 MB
    off += (size_t)Cp * D * 2;
    float* bias           = (float*)(ws + off);                   // [Cp]
    off += 4096;
    unsigned short* featsB = (unsigned short*)(ws + off);         // [N][D]   128 MB

    dim3 tb(32, 8);
    transpose_to_bf16<<<dim3(Cp / 32, Kp / 32), tb, 0, stream>>>(W, Wt, Kp, C, Cp);
    transpose_to_bf16<<<dim3(D / 32, Kp / 32), tb, 0, stream>>>(comp, compT, Kp, D, D);

    // FAT: GEMM1 (512 blocks, co-resident 2/CU) || feats convert (2048 blocks)
    fat_g1c<<<FAT_G1 + FAT_CV, 256, 0, stream>>>(Wt, compT, Mt, feats, featsB);

    bias_kernel<<<Cp, 256, 0, stream>>>(mean, Mt, bias, D);

    hipFuncSetAttribute(reinterpret_cast<const void*>(gemm2_p),
                        hipFuncAttributeMaxDynamicSharedMemorySize, P_LDS_BYTES);
    // GEMM2: out[8192][1000] = featsB @ Mt^T + bias ; grid 32x8 = 256 = 1/CU
    gemm2_p<<<(N / P_BM) * (Cp / P_BN), 512, P_LDS_BYTES, stream>>>(
        featsB, Mt, bias, out, N, Cp, D, C);
}